// Round 12
// baseline (3739.554 us; speedup 1.0000x reference)
//
#include <hip/hip_runtime.h>
#include <hip/hip_bf16.h>
#include <math.h>

#define S_LEN 4096
#define D_EMB 300
#define NG    600     // 4*HU
#define HDIM  300     // H
#define H2    600     // 2*H
#define VOCAB 100000

typedef float v4f __attribute__((ext_vector_type(4)));
typedef _Float16 f16x2 __attribute__((ext_vector_type(2)));
typedef _Float16 f16x8 __attribute__((ext_vector_type(8)));

__device__ __forceinline__ float bf2f(unsigned short u) {
  union { unsigned int i; float f; } v; v.i = ((unsigned int)u) << 16; return v.f;
}
__device__ __forceinline__ unsigned short f2bf(float f) {
  union { float f; unsigned int i; } v; v.f = f;
  return (unsigned short)((v.i + 0x7FFFu + ((v.i >> 16) & 1u)) >> 16);
}

// LDS-only barrier: drains lgkmcnt (LDS) but NOT vmcnt -> global loads/stores
// stay in flight across the barrier.
__device__ __forceinline__ void bar_lds() {
  asm volatile("s_waitcnt lgkmcnt(0)\n\ts_barrier" ::: "memory");
}

__global__ void zero_hh(float* __restrict__ HH) {
  if (threadIdx.x < 640) HH[threadIdx.x] = 0.f;
}
__global__ void zero_out_f(float* __restrict__ o, int n) {
  if ((int)threadIdx.x < n) o[threadIdx.x] = 0.f;
}

// ---- GEMM: C[M,N](bf16) = gather(A)[M,K] @ B[K,N](f32) + bias(f32) -----------
#define BM 64
#define BN 64
#define BK 16
template<bool A_BF16>
__global__ __launch_bounds__(256) void gemm_bias(
    const void* __restrict__ Av,
    const int* __restrict__ idx, int lda, int nrowsA,
    const float* __restrict__ B,
    const float* __restrict__ bias,
    unsigned short* __restrict__ C,
    int N, int K)
{
  __shared__ __align__(16) float As[BK][BM + 4];
  __shared__ __align__(16) float Bs[BK][BN + 4];
  __shared__ int rowidx[BM];

  int tid = threadIdx.x;
  int bm0 = blockIdx.y * BM, bn0 = blockIdx.x * BN;
  if (tid < BM) {
    int r = idx ? idx[bm0 + tid] : (bm0 + tid);
    r = (r < 0) ? 0 : ((r >= nrowsA) ? (nrowsA - 1) : r);
    rowidx[tid] = r;
  }
  __syncthreads();

  int tx  = tid & 15, ty = tid >> 4;
  int ar  = tid >> 2, akv = (tid & 3) << 2;
  int bkr = tid >> 4, bnv = (tid & 15) << 2;

  float acc[4][4] = {};
  for (int kk = 0; kk < K; kk += BK) {
    float a0=0.f, a1=0.f, a2=0.f, a3=0.f;
    int ka = kk + akv;
    if (ka < K) {
      if (A_BF16) {
        const unsigned short* A = (const unsigned short*)Av;
        ushort4 qa = *(const ushort4*)(A + (size_t)rowidx[ar]*lda + ka);
        a0 = bf2f(qa.x); a1 = bf2f(qa.y); a2 = bf2f(qa.z); a3 = bf2f(qa.w);
      } else {
        const float* A = (const float*)Av;
        float4 qa = *(const float4*)(A + (size_t)rowidx[ar]*lda + ka);
        a0 = qa.x; a1 = qa.y; a2 = qa.z; a3 = qa.w;
      }
    }
    float b0=0.f, b1=0.f, b2=0.f, b3=0.f;
    int kb = kk + bkr, nb = bn0 + bnv;
    if (kb < K && nb < N) {
      float4 qb = *(const float4*)(B + (size_t)kb*N + nb);
      b0 = qb.x; b1 = qb.y; b2 = qb.z; b3 = qb.w;
    }
    As[akv+0][ar] = a0; As[akv+1][ar] = a1; As[akv+2][ar] = a2; As[akv+3][ar] = a3;
    Bs[bkr][bnv+0] = b0; Bs[bkr][bnv+1] = b1; Bs[bkr][bnv+2] = b2; Bs[bkr][bnv+3] = b3;
    __syncthreads();
    #pragma unroll
    for (int k = 0; k < BK; ++k) {
      v4f av = *(const v4f*)&As[k][ty << 2];
      v4f bv = *(const v4f*)&Bs[k][tx << 2];
      #pragma unroll
      for (int i = 0; i < 4; ++i)
        #pragma unroll
        for (int j = 0; j < 4; ++j)
          acc[i][j] += av[i] * bv[j];
    }
    __syncthreads();
  }
  #pragma unroll
  for (int i = 0; i < 4; ++i) {
    int m = bm0 + (ty << 2) + i;
    #pragma unroll
    for (int j = 0; j < 4; ++j) {
      int n = bn0 + (tx << 2) + j;
      if (n < N) C[(size_t)m*N + n] = f2bf(acc[i][j] + bias[n]);
    }
  }
}

// ---- sequential biLSTM: one block per direction, MFMA f16 matvec -------------
// Phase A now runs on the MATRIX pipe instead of the VALU:
//   z(1x600) = h(1x150) @ U(150x600) tiled as 38 n-tiles x 5 k-tiles of
//   v_mfma_f32_16x16x32_f16 (190 mfma/step vs 750 half-rate fdot2 in r0).
//   - B fragments (U, f16) preloaded ONCE into VGPRs: wave w owns 3-4 n-tiles
//     (waves 0,1 get 3 — they also run BC), 5 k-tiles x 4 VGPR each.
//   - A fragment per k-tile: every lane ds_read_b128's the SAME per-group
//     16B chunk of h (broadcast, conflict-free). Rows 1..15 of A become
//     copies of h -> only affect D rows we never read.
//   - Layout robustness: for a matvec ANY bijective (group,elem)->k map works
//     as long as A and B share it (permutation cancels in sum over k).
//     Hard requirements: m/n = lane&15 (AMD standard) and the VERIFIED C/D
//     map col=lane&15,row=(lane>>4)*4+reg -> row 0 = lanes 0-15, reg 0.
//   - zrow gets the FULL dot product: BC reads 4 values (vs r0's 20-read
//     5-way reduce), then activations + cell update as in r0.
// Barriers (2/step), h_hist ring, pre prefetch: r0 exact.
__global__ __launch_bounds__(640) void lstm_kernel(
    const unsigned short* __restrict__ pre_f, const unsigned short* __restrict__ pre_b,
    const float* __restrict__ Uf, const float* __restrict__ Ub,
    unsigned short* __restrict__ hidden /* [S][300] bf16 */)
{
  const int dir = blockIdx.x;
  const unsigned short* pre = dir ? pre_b : pre_f;
  const float* U            = dir ? Ub : Uf;
  const int tid  = threadIdx.x;
  const int wave = tid >> 6, lane = tid & 63;

  __shared__ __align__(16) unsigned short h_u16[160];      // h as f16 (pad=0)
  __shared__ __align__(16) float zrow[608];                // full matvec result
  __shared__ __align__(16) unsigned short h_hist[8][160];  // bf16 h history

  const bool bc = tid < 150;

  // n-tile assignment over 10 waves: waves 0,1 -> 3 tiles; waves 2..9 -> 4
  const int ncnt   = (wave < 2) ? 3 : 4;
  const int nstart = (wave < 2) ? 3 * wave : 6 + 4 * (wave - 2);

  const int bgrp = lane >> 4;   // K lane-group (0..3)
  const int bn   = lane & 15;   // N within tile

  // preload B fragments (U as f16, MFMA B-operand layout k=8*bgrp+e, n=bn)
  f16x8 bfr[4][5];
  #pragma unroll
  for (int t = 0; t < 4; ++t) {
    #pragma unroll
    for (int kt = 0; kt < 5; ++kt) {
      f16x8 v;
      #pragma unroll
      for (int e = 0; e < 8; ++e) {
        int row = (kt << 5) + (bgrp << 3) + e;       // k
        int col = ((nstart + t) << 4) + bn;          // n (gate column j)
        float x = (t < ncnt && row < 150 && col < 600) ? U[(size_t)row*600 + col] : 0.f;
        v[e] = (_Float16)x;
      }
      bfr[t][kt] = v;
    }
  }

  const int t0 = dir ? (S_LEN - 1) : 0;
  const int dt = dir ? -1 : 1;
  const ptrdiff_t pstep = (ptrdiff_t)dt * 600;

  if (tid < 160) h_u16[tid] = 0;                 // h=0 (f16), incl. pad

  // BC-lane pre values in registers: pA = step s, pB = s+1, loaded ahead.
  float pA0=0,pA1=0,pA2=0,pA3=0, pB0=0,pB1=0,pB2=0,pB3=0;
  const unsigned short* pre2 = pre + (ptrdiff_t)t0*600 + 2*pstep;  // s+2 base
  if (bc) {
    const unsigned short* g0 = pre + (ptrdiff_t)t0*600;
    pA0 = bf2f(g0[tid]); pA1 = bf2f(g0[tid+150]);
    pA2 = bf2f(g0[tid+300]); pA3 = bf2f(g0[tid+450]);
    const unsigned short* g1 = g0 + pstep;
    pB0 = bf2f(g1[tid]); pB1 = bf2f(g1[tid+150]);
    pB2 = bf2f(g1[tid+300]); pB3 = bf2f(g1[tid+450]);
  }
  float c = 0.f;
  __syncthreads();

  const _Float16* hf = (const _Float16*)h_u16;

  for (int s8 = 0; s8 < S_LEN/8; ++s8) {
    // flush previous 8 steps' h (raw barriers never drain these stores)
    if (s8 && tid < 600) {
      int sub = tid / 75, w = (tid % 75) << 1;
      int sp  = (s8 << 3) - 8 + sub;
      int tp  = dir ? (S_LEN - 1 - sp) : sp;
      *(unsigned int*)(hidden + (size_t)tp*300 + dir*150 + w) =
          *(const unsigned int*)&h_hist[sub][w];
    }
    #pragma unroll
    for (int ss = 0; ss < 8; ++ss) {
      const int s = (s8 << 3) + ss;
      // ---- BC prefetch for step s+2 (global loads in flight under MFMA) ----
      float pC0=0,pC1=0,pC2=0,pC3=0;
      if (bc && s + 2 < S_LEN) {
        pC0 = bf2f(pre2[tid]);       pC1 = bf2f(pre2[tid+150]);
        pC2 = bf2f(pre2[tid+300]);   pC3 = bf2f(pre2[tid+450]);
      }
      // ---- Phase A: MFMA matvec z = h @ U (all 10 waves, matrix pipe) ----
      {
        v4f a0 = {0.f,0.f,0.f,0.f}, a1 = a0, a2 = a0, a3 = a0;
        #pragma unroll
        for (int kt = 0; kt < 5; ++kt) {
          f16x8 av = *(const f16x8*)&hf[(kt << 5) + (bgrp << 3)];
          a0 = __builtin_amdgcn_mfma_f32_16x16x32_f16(av, bfr[0][kt], a0, 0, 0, 0);
          a1 = __builtin_amdgcn_mfma_f32_16x16x32_f16(av, bfr[1][kt], a1, 0, 0, 0);
          a2 = __builtin_amdgcn_mfma_f32_16x16x32_f16(av, bfr[2][kt], a2, 0, 0, 0);
          if (ncnt == 4)
            a3 = __builtin_amdgcn_mfma_f32_16x16x32_f16(av, bfr[3][kt], a3, 0, 0, 0);
        }
        if (lane < 16) {                       // D row 0 = lanes 0-15, reg 0
          int base = (nstart << 4) + bn;
          zrow[base]      = a0[0];
          zrow[base + 16] = a1[0];
          zrow[base + 32] = a2[0];
          if (ncnt == 4) zrow[base + 48] = a3[0];
        }
      }
      bar_lds();

      // ---- Phase BC: gate activations + cell update (150 lanes) ----
      if (bc) {
        float zi = pA0 + zrow[tid];
        float zff= pA1 + zrow[150 + tid];
        float zg = pA2 + zrow[300 + tid];
        float zo = pA3 + zrow[450 + tid];
        float gi = __builtin_amdgcn_rcpf(1.f + __expf(-zi));
        float gf = __builtin_amdgcn_rcpf(1.f + __expf(-zff));
        float gg = 1.f - 2.f * __builtin_amdgcn_rcpf(__expf(2.f * zg) + 1.f);
        float go = __builtin_amdgcn_rcpf(1.f + __expf(-zo));
        c = gf * c + gi * gg;
        float th = 1.f - 2.f * __builtin_amdgcn_rcpf(__expf(2.f * c) + 1.f);
        float hv = go * th;
        ((_Float16*)h_u16)[tid] = (_Float16)hv;
        h_hist[ss][tid] = f2bf(hv);
        pA0 = pB0; pA1 = pB1; pA2 = pB2; pA3 = pB3;
        pB0 = pC0; pB1 = pC1; pB2 = pC2; pB3 = pC3;
      }
      bar_lds();
      pre2 += pstep;
    }
  }

  // final flush (steps 4088..4095); stores drain at kernel end
  if (tid < 600) {
    int sub = tid / 75, w = (tid % 75) << 1;
    int sp  = S_LEN - 8 + sub;
    int tp  = dir ? (S_LEN - 1 - sp) : sp;
    *(unsigned int*)(hidden + (size_t)tp*300 + dir*150 + w) =
        *(const unsigned int*)&h_hist[sub][w];
  }
}

// ---- per-word primary+secondary attention; atomic-reduce into HH -------------
__global__ __launch_bounds__(128) void attn_word(
    const unsigned short* __restrict__ outp,   // [S][300] bf16
    const unsigned short* __restrict__ hid,    // [S][300] bf16
    const float* __restrict__ E,               // [V][300] f32
    const int* __restrict__ syn,               // [S][4]
    const float* __restrict__ W_s,             // [600]
    const float* __restrict__ b_s,             // [1]
    float* __restrict__ HH)                    // [600] accumulator
{
  int t = blockIdx.x, tid = threadIdx.x;
  __shared__ float s_out[300], s_hid[300], s_syn[4][300], s_m[300];
  __shared__ float s_red[8], s_sc[4], s_cf;

  int r0 = syn[t*4+0], r1 = syn[t*4+1], r2 = syn[t*4+2], r3 = syn[t*4+3];
  r0 = (r0 < 0) ? 0 : ((r0 >= VOCAB) ? VOCAB-1 : r0);
  r1 = (r1 < 0) ? 0 : ((r1 >= VOCAB) ? VOCAB-1 : r1);
  r2 = (r2 < 0) ? 0 : ((r2 >= VOCAB) ? VOCAB-1 : r2);
  r3 = (r3 < 0) ? 0 : ((r3 >= VOCAB) ? VOCAB-1 : r3);
  for (int d = tid; d < 300; d += 128) {
    s_out[d] = bf2f(outp[(size_t)t*300 + d]);
    s_hid[d] = bf2f(hid[(size_t)t*300 + d]);
    s_syn[0][d] = E[(size_t)r0*300 + d];
    s_syn[1][d] = E[(size_t)r1*300 + d];
    s_syn[2][d] = E[(size_t)r2*300 + d];
    s_syn[3][d] = E[(size_t)r3*300 + d];
  }
  __syncthreads();

  float p0=0.f, p1=0.f, p2=0.f, p3=0.f;
  for (int d = tid; d < 300; d += 128) {
    float o = s_out[d];
    p0 += o*s_syn[0][d]; p1 += o*s_syn[1][d];
    p2 += o*s_syn[2][d]; p3 += o*s_syn[3][d];
  }
  #pragma unroll
  for (int off = 32; off; off >>= 1) {
    p0 += __shfl_down(p0, off); p1 += __shfl_down(p1, off);
    p2 += __shfl_down(p2, off); p3 += __shfl_down(p3, off);
  }
  int wave = tid >> 6, lane = tid & 63;
  if (lane == 0) {
    s_red[wave*4+0] = p0; s_red[wave*4+1] = p1;
    s_red[wave*4+2] = p2; s_red[wave*4+3] = p3;
  }
  __syncthreads();
  if (tid < 4) s_sc[tid] = __expf(fminf(s_red[tid] + s_red[4 + tid], 50.f));
  __syncthreads();

  float sc0 = s_sc[0], sc1 = s_sc[1], sc2 = s_sc[2], sc3 = s_sc[3];
  float cp = 0.f;
  for (int d = tid; d < 300; d += 128) {
    float m = sc0*s_syn[0][d] + sc1*s_syn[1][d] + sc2*s_syn[2][d] + sc3*s_syn[3][d];
    s_m[d] = m;
    cp += s_hid[d]*W_s[d] + m*W_s[300 + d];
  }
  #pragma unroll
  for (int off = 32; off; off >>= 1) cp += __shfl_down(cp, off);
  if (lane == 0) s_red[wave] = cp;
  __syncthreads();
  if (tid == 0) s_cf = __expf(tanhf(s_red[0] + s_red[1] + b_s[0]));
  __syncthreads();

  float cf = s_cf;
  for (int d = tid; d < 300; d += 128) {
    atomicAdd(&HH[d],       cf * s_hid[d]);
    atomicAdd(&HH[300 + d], cf * s_m[d]);
  }
}

// ---- output heads ------------------------------------------------------------
__global__ void heads(const float* __restrict__ HH,
                      const float* __restrict__ W_emo, const float* __restrict__ b_emo,
                      const float* __restrict__ W_sent, const float* __restrict__ b_sent,
                      float* __restrict__ out) {
  int tid = threadIdx.x;
  if (tid < 8) {
    float a = 0.f;
    for (int d = 0; d < H2; ++d) a += HH[d] * W_emo[d*8 + tid];
    out[tid] = a + b_emo[tid];
  } else if (tid == 8) {
    float a = 0.f;
    for (int d = 0; d < H2; ++d) a += HH[d] * W_sent[d];
    out[8] = a + b_sent[0];
  }
}

extern "C" void kernel_launch(void* const* d_in, const int* in_sizes, int n_in,
                              void* d_out, int out_size, void* d_ws, size_t ws_size,
                              hipStream_t stream) {
  const int*   sentence = (const int*)d_in[0];
  const int*   syn_idx  = (const int*)d_in[1];
  const float* E        = (const float*)d_in[2];
  const float* W_f      = (const float*)d_in[3];
  const float* U_f      = (const float*)d_in[4];
  const float* b_f      = (const float*)d_in[5];
  const float* W_b      = (const float*)d_in[6];
  const float* U_b      = (const float*)d_in[7];
  const float* b_b      = (const float*)d_in[8];
  const float* W_p      = (const float*)d_in[9];
  const float* b_p      = (const float*)d_in[10];
  const float* W_s      = (const float*)d_in[11];
  const float* b_s      = (const float*)d_in[12];
  const float* W_emo    = (const float*)d_in[13];
  const float* b_emo    = (const float*)d_in[14];
  const float* W_sent   = (const float*)d_in[15];
  const float* b_sent   = (const float*)d_in[16];
  float*       outv     = (float*)d_out;

  // workspace layout (16B-aligned, 14,748,160 B total)
  unsigned char* ws = (unsigned char*)d_ws;
  float*          HH     = (float*)ws;
  unsigned short* hidden = (unsigned short*)(ws + 2560);
  unsigned short* out_p  = (unsigned short*)(ws + 2460160);
  unsigned short* pre_f  = (unsigned short*)(ws + 4917760);
  unsigned short* pre_b  = (unsigned short*)(ws + 9832960);

  if (ws_size < 14748160u) {
    zero_out_f<<<1, 64, 0, stream>>>(outv, out_size);
    return;
  }

  zero_hh<<<1, 640, 0, stream>>>(HH);
  gemm_bias<false><<<dim3(10, 64), 256, 0, stream>>>(
      (const void*)E, sentence, D_EMB, VOCAB, W_f, b_f, pre_f, NG, D_EMB);
  gemm_bias<false><<<dim3(10, 64), 256, 0, stream>>>(
      (const void*)E, sentence, D_EMB, VOCAB, W_b, b_b, pre_b, NG, D_EMB);
  lstm_kernel<<<2, 640, 0, stream>>>(pre_f, pre_b, U_f, U_b, hidden);
  gemm_bias<true><<<dim3(5, 64), 256, 0, stream>>>(
      (const void*)hidden, nullptr, HDIM, S_LEN, W_p, b_p, out_p, HDIM, HDIM);
  attn_word<<<S_LEN, 128, 0, stream>>>(out_p, hidden, E, syn_idx, W_s, b_s, HH);
  heads<<<1, 64, 0, stream>>>(HH, W_emo, b_emo, W_sent, b_sent, outv);
}